// Round 7
// baseline (1498.670 us; speedup 1.0000x reference)
//
#include <hip/hip_runtime.h>
#include <math.h>

#define EPS 1e-8f

typedef _Float16 h2_t __attribute__((ext_vector_type(2)));
typedef _Float16 half8 __attribute__((ext_vector_type(8)));
typedef float f32x4 __attribute__((ext_vector_type(4)));

__device__ __forceinline__ float fsig(float x)  { return 1.0f / (1.0f + __expf(-x)); }
__device__ __forceinline__ float ftanh(float x) { return 1.0f - 2.0f / (1.0f + __expf(2.0f * x)); }

// ---------------------------------------------------------------------------
// Weight prep: stack fwd/bwd W_ih into fp16 [768,320pad] / [768,512] + biases.
// ---------------------------------------------------------------------------
__global__ __launch_bounds__(256) void prep_w_k(
    const float* __restrict__ rwf, const float* __restrict__ rwb,
    const float* __restrict__ awf, const float* __restrict__ awb,
    const float* __restrict__ rbf, const float* __restrict__ rbb,
    const float* __restrict__ abf, const float* __restrict__ abb,
    _Float16* __restrict__ wrh, _Float16* __restrict__ wah,
    float* __restrict__ br, float* __restrict__ ba)
{
    int idx = blockIdx.x * 256 + threadIdx.x;
    if (idx < 768 * 320) {
        int g = idx / 320, k = idx % 320;
        float v = 0.f;
        if (k < 300) v = (g < 384) ? rwf[g * 300 + k] : rwb[(g - 384) * 300 + k];
        wrh[idx] = (_Float16)v;
    }
    if (idx < 768 * 512) {
        int g = idx / 512, k = idx % 512;
        wah[idx] = (_Float16)((g < 384) ? awf[g * 512 + k] : awb[(g - 384) * 512 + k]);
    }
    if (idx < 768) {
        br[idx] = (idx < 384) ? rbf[idx] : rbb[idx - 384];
        ba[idx] = (idx < 384) ? abf[idx] : abb[idx - 384];
    }
}

// ---------------------------------------------------------------------------
// fp16 MFMA GEMM, 64x64 tile, BK=32, 256 threads = 4 waves (2x2 of 32x32).
// C[z] = A[z] * B[z/bdiv]^T + bias, fp32 accumulate, fp16 out.
// AF32:   A is fp32, converted to fp16 during staging, zero-pad k>=Kreal.
// TRBS:   B given as [K][N] row-major -> transpose-stage into LDS.
// SPLITA: A = [A|A2] along K (each lda wide, fp16).
// Layouts (16x16x32 f16): A/B frag m|n=lane&15, k=(lane>>4)*8+j;
// C/D col=lane&15, row=(lane>>4)*4+reg.  [m89/m91-verified]
// ---------------------------------------------------------------------------
template <bool AF32, bool TRBS, bool SPLITA, bool HASBIAS>
__global__ __launch_bounds__(256, 4) void hgemm_k(
    const void* __restrict__ A, const _Float16* __restrict__ A2,
    const _Float16* __restrict__ B, const float* __restrict__ bias,
    _Float16* __restrict__ C, int M, int N, int K, int Kreal,
    int lda, int ldb, int ldc, long sA, long sB, int bdiv, long sC)
{
    const int jn = blockIdx.x * 64;
    const int im = blockIdx.y * 64;
    const int z  = blockIdx.z;
    const _Float16* Bb = B + (size_t)(z / bdiv) * sB;
    _Float16* Cb = C + (size_t)z * sC;

    __shared__ __align__(16) _Float16 As[64 * 32];
    __shared__ __align__(16) _Float16 Bs[64 * 32];

    const int tid  = threadIdx.x;
    const int arow = tid >> 2;          // 0..63
    const int akof = (tid & 3) * 8;     // 0,8,16,24
    const int lane = tid & 63;
    const int wv   = tid >> 6;          // 0..3
    const int wm   = (wv & 1) * 32;
    const int wn   = (wv >> 1) * 32;
    const int fm   = lane & 15;
    const int quad = lane >> 4;

    f32x4 acc[2][2];
#pragma unroll
    for (int a = 0; a < 2; a++)
#pragma unroll
        for (int b = 0; b < 2; b++) acc[a][b] = (f32x4)0.f;

    for (int k0 = 0; k0 < K; k0 += 32) {
        // ---- A tile
        {
            half8 av = (half8)(_Float16)0.f;
            const int row = im + arow;
            if (row < M) {
                const int kg = k0 + akof;
                if constexpr (AF32) {
                    const float* af = (const float*)A + (size_t)z * sA + (size_t)row * lda;
#pragma unroll
                    for (int e = 0; e < 8; e++)
                        av[e] = (kg + e < Kreal) ? (_Float16)af[kg + e] : (_Float16)0.f;
                } else if constexpr (SPLITA) {
                    const _Float16* Ah  = (const _Float16*)A + (size_t)z * sA;
                    const _Float16* A2h = A2 + (size_t)z * sA;
                    const _Float16* ap = (kg < 256) ? (Ah + (size_t)row * lda + kg)
                                                    : (A2h + (size_t)row * lda + (kg - 256));
                    av = *(const half8*)ap;
                } else {
                    const _Float16* Ah = (const _Float16*)A + (size_t)z * sA;
                    av = *(const half8*)(Ah + (size_t)row * lda + kg);
                }
            }
            *(half8*)&As[arow * 32 + akof] = av;
        }
        // ---- B tile
        if constexpr (!TRBS) {          // B [N][K] rm (NT)
            half8 bv = *(const half8*)(Bb + (size_t)(jn + arow) * ldb + k0 + akof);
            *(half8*)&Bs[arow * 32 + akof] = bv;
        } else {                        // B [K][N] rm -> LDS [n][k]
            const int kk = tid >> 3, noff = (tid & 7) * 8;
            half8 bv = *(const half8*)(Bb + (size_t)(k0 + kk) * ldb + jn + noff);
#pragma unroll
            for (int e = 0; e < 8; e++) Bs[(noff + e) * 32 + kk] = bv[e];
        }
        __syncthreads();

        const _Float16* Asp = As + (wm + fm) * 32 + quad * 8;
        const _Float16* Bsp = Bs + (wn + fm) * 32 + quad * 8;
        half8 a0 = *(const half8*)Asp;
        half8 a1 = *(const half8*)(Asp + 16 * 32);
        half8 b0 = *(const half8*)Bsp;
        half8 b1 = *(const half8*)(Bsp + 16 * 32);
        acc[0][0] = __builtin_amdgcn_mfma_f32_16x16x32_f16(a0, b0, acc[0][0], 0, 0, 0);
        acc[0][1] = __builtin_amdgcn_mfma_f32_16x16x32_f16(a0, b1, acc[0][1], 0, 0, 0);
        acc[1][0] = __builtin_amdgcn_mfma_f32_16x16x32_f16(a1, b0, acc[1][0], 0, 0, 0);
        acc[1][1] = __builtin_amdgcn_mfma_f32_16x16x32_f16(a1, b1, acc[1][1], 0, 0, 0);
        __syncthreads();
    }

#pragma unroll
    for (int tm = 0; tm < 2; tm++) {
#pragma unroll
        for (int tn = 0; tn < 2; tn++) {
            const int col  = jn + wn + tn * 16 + fm;
            const int row0 = im + wm + tm * 16 + quad * 4;
            const float bv = HASBIAS ? bias[col] : 0.f;
#pragma unroll
            for (int r = 0; r < 4; r++) {
                const int row = row0 + r;
                if (row < M)
                    Cb[(size_t)row * ldc + col] = (_Float16)(acc[tm][tn][r] + bv);
            }
        }
    }
}

// ---------------------------------------------------------------------------
// GRU recurrence v5. One block per (seq,dir); 512 threads = 128 owners x 4
// k-slices; fp16x2 weights in VGPRs + v_dot2_f32_f16. NEW: gx staged into LDS
// in 32-step tiles and outs buffered in LDS + bulk-flushed, so the per-step
// barrier path has NO global ops in flight (v4 drained a ~900cyc cold gx load
// at vmcnt(0) before EVERY s_barrier -> 1830cyc/step).
// ---------------------------------------------------------------------------
__global__ __launch_bounds__(512, 2) void gru_rec_k(
    const _Float16* __restrict__ gx,
    const float* __restrict__ whh_f, const float* __restrict__ whh_b,
    const float* __restrict__ bhh_f, const float* __restrict__ bhh_b,
    _Float16* __restrict__ outs_h, float* __restrict__ hfin, int L)
{
    const int dir = blockIdx.x & 1;
    const int s   = blockIdx.x >> 1;
    const int t   = threadIdx.x;
    const int i   = t & 127;
    const int c   = t >> 7;
    const float* W  = dir ? whh_b : whh_f;
    const float* bh = dir ? bhh_b : bhh_f;

    h2_t w2[3][16];
#pragma unroll
    for (int j = 0; j < 3; j++) {
        const float* Wr = W + (size_t)(i + 128 * j) * 128 + 32 * c;
#pragma unroll
        for (int q = 0; q < 16; q++) {
            float2 f = *(const float2*)(Wr + 2 * q);
            h2_t p; p.x = (_Float16)f.x; p.y = (_Float16)f.y;
            w2[j][q] = p;
        }
    }
    float b3[3] = {0.f, 0.f, 0.f};
    if (c == 0) {
#pragma unroll
        for (int j = 0; j < 3; j++) b3[j] = bh[i + 128 * j];
    }

    __shared__ __align__(16) float hs[128];
    __shared__ __align__(4) _Float16 h1[128];
    __shared__ float sp[3][384];
    __shared__ __align__(16) _Float16 gxs[32][384];
    __shared__ __align__(16) _Float16 outb[32][128];
    if (t < 128) { hs[t] = 0.0f; h1[t] = (_Float16)0.0f; }

    for (int t0 = 0; t0 < L; t0 += 32) {
        const int Tc = (L - t0 < 32) ? (L - t0) : 32;
        // ---- stage gx tile (Tc*48 half8 chunks over 512 threads)
#pragma unroll
        for (int r = 0; r < 3; r++) {
            const int q = t + 512 * r;
            if (q < Tc * 48) {
                const int j = q / 48, off = (q % 48) * 8;
                const int tt = dir ? (L - 1 - (t0 + j)) : (t0 + j);
                *(half8*)&gxs[j][off] =
                    *(const half8*)(gx + ((size_t)s * L + tt) * 768 + dir * 384 + off);
            }
        }
        __syncthreads();   // drains staging loads once per tile; covers h init

        for (int j = 0; j < Tc; j++) {
            const h2_t* hp = (const h2_t*)h1 + 16 * c;
            float a0 = 0.f, a1 = 0.f, a2 = 0.f;
#pragma unroll
            for (int q = 0; q < 16; q++) {
                h2_t hq = hp[q];
                a0 = __builtin_amdgcn_fdot2(w2[0][q], hq, a0, false);
                a1 = __builtin_amdgcn_fdot2(w2[1][q], hq, a1, false);
                a2 = __builtin_amdgcn_fdot2(w2[2][q], hq, a2, false);
            }
            if (c != 0) {
                sp[c - 1][i]       = a0;
                sp[c - 1][i + 128] = a1;
                sp[c - 1][i + 256] = a2;
            }
            __syncthreads();
            if (c == 0) {
                float gh0 = a0 + sp[0][i]       + sp[1][i]       + sp[2][i]       + b3[0];
                float gh1 = a1 + sp[0][i + 128] + sp[1][i + 128] + sp[2][i + 128] + b3[1];
                float gh2 = a2 + sp[0][i + 256] + sp[1][i + 256] + sp[2][i + 256] + b3[2];
                float xc0 = (float)gxs[j][i];
                float xc1 = (float)gxs[j][i + 128];
                float xc2 = (float)gxs[j][i + 256];
                float r = fsig(xc0 + gh0);
                float zz = fsig(xc1 + gh1);
                float n = ftanh(xc2 + r * gh2);
                float hnew = (1.0f - zz) * n + zz * hs[i];
                hs[i] = hnew;
                h1[i] = (_Float16)hnew;
                outb[j][i] = (_Float16)hnew;
            }
            __syncthreads();
        }

        // ---- bulk flush outs tile (Tc*16 half8 chunks)
        if (outs_h && t < Tc * 16) {
            const int j = t / 16, off = (t % 16) * 8;
            const int tt = dir ? (L - 1 - (t0 + j)) : (t0 + j);
            *(half8*)(outs_h + ((size_t)s * L + tt) * 256 + dir * 128 + off) =
                *(const half8*)&outb[j][off];
        }
        // next staging barrier orders outb reads vs. next tile's gate writes
    }
    if (hfin && c == 0) hfin[(size_t)s * 256 + dir * 128 + i] = hs[i];
}

// ---------------------------------------------------------------------------
// Row inverse norms over fp16 rows of 256.
// ---------------------------------------------------------------------------
__global__ __launch_bounds__(256) void rowinv_k(const _Float16* __restrict__ x,
                                                float* __restrict__ rinv)
{
    const int row = blockIdx.x;
    float v = (float)x[(size_t)row * 256 + threadIdx.x];
    float ss = v * v;
#pragma unroll
    for (int o = 32; o > 0; o >>= 1) ss += __shfl_down(ss, o);
    __shared__ float ps[4];
    if ((threadIdx.x & 63) == 0) ps[threadIdx.x >> 6] = ss;
    __syncthreads();
    if (threadIdx.x == 0)
        rinv[row] = 1.0f / fmaxf(sqrtf(ps[0] + ps[1] + ps[2] + ps[3]), EPS);
}

// ---------------------------------------------------------------------------
// Fused cosine-scale + softmax (fp16 in/out, 512 positions).
// ---------------------------------------------------------------------------
__global__ __launch_bounds__(256) void att_softmax_k(
    _Float16* __restrict__ att, const float* __restrict__ rinv_opt_l,
    const float* __restrict__ rinv_ctx, int sbase)
{
    const int row = blockIdx.x;
    const int b = (sbase + row / 50) / 10;
    _Float16* p = att + (size_t)row * 512;
    const float* rc = rinv_ctx + b * 512;
    const float sA = rinv_opt_l[row];
    const int t = threadIdx.x;

    float v0 = (float)p[t]       * (sA * rc[t]);
    float v1 = (float)p[t + 256] * (sA * rc[t + 256]);

    __shared__ float red[4];
    float m = fmaxf(v0, v1);
#pragma unroll
    for (int o = 32; o > 0; o >>= 1) m = fmaxf(m, __shfl_down(m, o));
    if ((t & 63) == 0) red[t >> 6] = m;
    __syncthreads();
    m = fmaxf(fmaxf(red[0], red[1]), fmaxf(red[2], red[3]));
    float e0 = __expf(v0 - m), e1 = __expf(v1 - m);
    float ssum = e0 + e1;
#pragma unroll
    for (int o = 32; o > 0; o >>= 1) ssum += __shfl_down(ssum, o);
    __syncthreads();
    if ((t & 63) == 0) red[t >> 6] = ssum;
    __syncthreads();
    float inv = 1.0f / (red[0] + red[1] + red[2] + red[3]);
    p[t]       = (_Float16)(e0 * inv);
    p[t + 256] = (_Float16)(e1 * inv);
}

// ---------------------------------------------------------------------------
// logits[s] = cosine(ctx_h[s/10], ao_h[s])
// ---------------------------------------------------------------------------
__global__ __launch_bounds__(256) void logits_k(const float* __restrict__ ch,
                                                const float* __restrict__ ah,
                                                float* __restrict__ logits)
{
    const int s = blockIdx.x;
    const int b = s / 10;
    const int t = threadIdx.x;
    float a = ch[b * 256 + t];
    float c = ah[(size_t)s * 256 + t];
    float num = a * c, na = a * a, nc = c * c;
#pragma unroll
    for (int o = 32; o > 0; o >>= 1) {
        num += __shfl_down(num, o);
        na  += __shfl_down(na,  o);
        nc  += __shfl_down(nc,  o);
    }
    __shared__ float pn[4], pa[4], pc[4];
    if ((t & 63) == 0) { pn[t >> 6] = num; pa[t >> 6] = na; pc[t >> 6] = nc; }
    __syncthreads();
    if (t == 0) {
        float sn = pn[0] + pn[1] + pn[2] + pn[3];
        float sa = pa[0] + pa[1] + pa[2] + pa[3];
        float sc = pc[0] + pc[1] + pc[2] + pc[3];
        logits[s] = sn / (fmaxf(sqrtf(sa), EPS) * fmaxf(sqrtf(sc), EPS));
    }
}

// ---------------------------------------------------------------------------
__global__ __launch_bounds__(64) void soft10_k(const float* __restrict__ logits,
                                               float* __restrict__ out)
{
    const int b = blockIdx.x;
    const int t = threadIdx.x;
    __shared__ float v[10];
    if (t < 10) v[t] = logits[b * 10 + t];
    __syncthreads();
    if (t < 10) {
        float m = v[0];
#pragma unroll
        for (int i = 1; i < 10; i++) m = fmaxf(m, v[i]);
        float ssum = 0.f;
#pragma unroll
        for (int i = 0; i < 10; i++) ssum += __expf(v[i] - m);
        out[b * 10 + t] = __expf(v[t] - m) / ssum;
    }
}

// ---------------------------------------------------------------------------
extern "C" void kernel_launch(void* const* d_in, const int* in_sizes, int n_in,
                              void* d_out, int out_size, void* d_ws, size_t ws_size,
                              hipStream_t stream)
{
    const float* context = (const float*)d_in[0];
    const float* options = (const float*)d_in[2];
    const float* rw_ih_f = (const float*)d_in[4];
    const float* rw_hh_f = (const float*)d_in[5];
    const float* rb_ih_f = (const float*)d_in[6];
    const float* rb_hh_f = (const float*)d_in[7];
    const float* rw_ih_b = (const float*)d_in[8];
    const float* rw_hh_b = (const float*)d_in[9];
    const float* rb_ih_b = (const float*)d_in[10];
    const float* rb_hh_b = (const float*)d_in[11];
    const float* aw_ih_f = (const float*)d_in[12];
    const float* aw_hh_f = (const float*)d_in[13];
    const float* ab_ih_f = (const float*)d_in[14];
    const float* ab_hh_f = (const float*)d_in[15];
    const float* aw_ih_b = (const float*)d_in[16];
    const float* aw_hh_b = (const float*)d_in[17];
    const float* ab_ih_b = (const float*)d_in[18];
    const float* ab_hh_b = (const float*)d_in[19];

    // --- chunk config. persist(fl) = 4,760,960 (~19 MB, fp16 input copies
    //     removed: hgemm AF32 reads fp32 inputs directly).
    //     pool = max(bc*196608, sc*19200) fl; extras = sc*25600 fl.
    const size_t persist = 4760960;
    static const int cands[8][2] = {{1,2},{1,4},{1,8},{2,8},{2,16},{4,16},{8,16},{8,16}};
    int CC = 8, OC = 16;
    for (int idx = 0; idx < 8; idx++) {
        size_t bc_ = 64 / cands[idx][0], sc_ = 640 / cands[idx][1];
        size_t p = bc_ * 196608;
        if (sc_ * 19200 > p) p = sc_ * 19200;
        if ((persist + p + sc_ * 25600) * 4 <= ws_size) {
            CC = cands[idx][0]; OC = cands[idx][1]; break;
        }
    }
    const int bc = 64 / CC;
    const int sc = 640 / OC;
    size_t poolsz = (size_t)bc * 196608;
    if ((size_t)sc * 19200 > poolsz) poolsz = (size_t)sc * 19200;

    float* ws = (float*)d_ws;
    size_t off = 0;
    _Float16* wrh   = (_Float16*)(ws + off); off += 122880;   // [768][320] h
    float*    br    = ws + off;              off += 768;
    _Float16* wah   = (_Float16*)(ws + off); off += 196608;   // [768][512] h
    float*    ba    = ws + off;              off += 768;
    _Float16* couts = (_Float16*)(ws + off); off += 4194304;  // [64*512][256] h
    float*    ctxhf = ws + off;              off += 16384;    // ctx h_fin
    float*    aohf  = ws + off;              off += 163840;   // ao h_fin
    float*    logits= ws + off;              off += 640;
    float*    rinvc = ws + off;              off += 32768;
    float*    rinvo = ws + off;              off += 32000;
    _Float16* POOL  = (_Float16*)(ws + off); off += poolsz;   // gx (ctx/opt/attn)
    _Float16* ATT   = (_Float16*)(ws + off); off += (size_t)sc * 12800;
    _Float16* P2H   = (_Float16*)(ws + off); off += (size_t)sc * 6400;
    _Float16* P3H   = (_Float16*)(ws + off); off += (size_t)sc * 6400;

    // 1. weights -> fp16 (padded K=320)
    prep_w_k<<<1536, 256, 0, stream>>>(rw_ih_f, rw_ih_b, aw_ih_f, aw_ih_b,
                                       rb_ih_f, rb_ih_b, ab_ih_f, ab_ih_b,
                                       wrh, wah, br, ba);

    // 2. context: gx GEMM (MFMA, fp32 A) + GRU per chunk
    for (int c = 0; c < CC; c++) {
        const int Mc = bc * 512;
        hgemm_k<true, false, false, true><<<dim3(12, Mc / 64, 1), 256, 0, stream>>>(
            context + (size_t)c * Mc * 300, nullptr, wrh, br, POOL,
            Mc, 768, 320, 300, 300, 320, 768, 0, 0, 1, 0);
        gru_rec_k<<<2 * bc, 512, 0, stream>>>(
            POOL, rw_hh_f, rw_hh_b, rb_hh_f, rb_hh_b,
            couts + (size_t)c * Mc * 256, ctxhf + (size_t)c * bc * 256, 512);
    }

    // 3. ctx row inverse norms
    rowinv_k<<<32768, 256, 0, stream>>>(couts, rinvc);

    // 4. options: per chunk pipeline
    for (int o = 0; o < OC; o++) {
        const int base = o * sc;
        const int Mo = sc * 50;
        const _Float16* ctxB = couts + (size_t)(base / 10) * 131072;

        // 4a. opt gx (MFMA, fp32 A) -> POOL
        hgemm_k<true, false, false, true><<<dim3(12, (Mo + 63) / 64, 1), 256, 0, stream>>>(
            options + (size_t)base * 50 * 300, nullptr, wrh, br, POOL,
            Mo, 768, 320, 300, 300, 320, 768, 0, 0, 1, 0);
        // 4b. opt GRU -> P2H
        gru_rec_k<<<2 * sc, 512, 0, stream>>>(
            POOL, rw_hh_f, rw_hh_b, rb_hh_f, rb_hh_b, P2H, nullptr, 50);
        // 4c. opt row inverse norms
        rowinv_k<<<Mo, 256, 0, stream>>>(P2H, rinvo + (size_t)base * 50);
        // 4d. raw scores (MFMA, NT, batched): ATT = P2H @ ctxB^T
        hgemm_k<false, false, false, false><<<dim3(8, 1, sc), 256, 0, stream>>>(
            P2H, nullptr, ctxB, nullptr, ATT,
            50, 512, 256, 256, 256, 256, 512, 12800, 131072, 10, 25600);
        // 4e. fused cosine scaling + softmax (fp16 in-place)
        att_softmax_k<<<Mo, 256, 0, stream>>>(ATT, rinvo + (size_t)base * 50,
                                              rinvc, base);
        // 4f. att_opt (MFMA, NN via transpose-stage): P3H = ATT @ ctxB
        hgemm_k<false, true, false, false><<<dim3(4, 1, sc), 256, 0, stream>>>(
            ATT, nullptr, ctxB, nullptr, P3H,
            50, 256, 512, 512, 512, 256, 256, 25600, 131072, 10, 12800);
        // 4g. attn gx (MFMA, split-A K=512): POOL = [P3H|P2H] @ wah^T + ba
        hgemm_k<false, false, true, true><<<dim3(12, (Mo + 63) / 64, 1), 256, 0, stream>>>(
            P3H, P2H, wah, ba, POOL,
            Mo, 768, 512, 512, 256, 512, 768, 0, 0, 1, 0);
        // 4h. attn GRU -> ao_h
        gru_rec_k<<<2 * sc, 512, 0, stream>>>(
            POOL, aw_hh_f, aw_hh_b, ab_hh_f, ab_hh_b,
            nullptr, aohf + (size_t)base * 256, 50);
    }

    // 5. cosine logits + final softmax
    logits_k<<<640, 256, 0, stream>>>(ctxhf, aohf, logits);
    soft10_k<<<64, 64, 0, stream>>>(logits, (float*)d_out);
}

// Round 9
// 1354.063 us; speedup vs baseline: 1.1068x; 1.1068x over previous
//
#include <hip/hip_runtime.h>
#include <math.h>

#define EPS 1e-8f

typedef _Float16 h2_t __attribute__((ext_vector_type(2)));
typedef _Float16 half8 __attribute__((ext_vector_type(8)));
typedef float f32x4 __attribute__((ext_vector_type(4)));

__device__ __forceinline__ float fsig(float x)  { return 1.0f / (1.0f + __expf(-x)); }
__device__ __forceinline__ float ftanh(float x) { return 1.0f - 2.0f / (1.0f + __expf(2.0f * x)); }

// ---------------------------------------------------------------------------
// Weight prep: W_ih stacks -> fp16 [768,320pad]/[768,512]; W_hh -> fp16
// [2][384][128]; biases fp32.
// ---------------------------------------------------------------------------
__global__ __launch_bounds__(256) void prep_w_k(
    const float* __restrict__ rwf, const float* __restrict__ rwb,
    const float* __restrict__ awf, const float* __restrict__ awb,
    const float* __restrict__ rbf, const float* __restrict__ rbb,
    const float* __restrict__ abf, const float* __restrict__ abb,
    const float* __restrict__ rhf, const float* __restrict__ rhb,
    const float* __restrict__ ahf, const float* __restrict__ ahb,
    _Float16* __restrict__ wrh, _Float16* __restrict__ wah,
    _Float16* __restrict__ wr16, _Float16* __restrict__ wa16,
    float* __restrict__ br, float* __restrict__ ba)
{
    int idx = blockIdx.x * 256 + threadIdx.x;
    if (idx < 768 * 320) {
        int g = idx / 320, k = idx % 320;
        float v = 0.f;
        if (k < 300) v = (g < 384) ? rwf[g * 300 + k] : rwb[(g - 384) * 300 + k];
        wrh[idx] = (_Float16)v;
    }
    if (idx < 768 * 512) {
        int g = idx / 512, k = idx % 512;
        wah[idx] = (_Float16)((g < 384) ? awf[g * 512 + k] : awb[(g - 384) * 512 + k]);
    }
    if (idx < 2 * 384 * 128) {
        int d = idx / 49152, r = idx % 49152;
        wr16[idx] = (_Float16)(d ? rhb[r] : rhf[r]);
        wa16[idx] = (_Float16)(d ? ahb[r] : ahf[r]);
    }
    if (idx < 768) {
        br[idx] = (idx < 384) ? rbf[idx] : rbb[idx - 384];
        ba[idx] = (idx < 384) ? abf[idx] : abb[idx - 384];
    }
}

// ---------------------------------------------------------------------------
// Input conversion fp32 -> fp16 (K padded 300->320 with zeros).
// ---------------------------------------------------------------------------
__global__ __launch_bounds__(256) void conv_k(
    const float* __restrict__ ctx, const float* __restrict__ opt,
    _Float16* __restrict__ ctxh, _Float16* __restrict__ opth)
{
    int idx = blockIdx.x * 256 + threadIdx.x;
    if (idx < 32768 * 320) {
        int r = idx / 320, k = idx % 320;
        ctxh[idx] = (k < 300) ? (_Float16)ctx[r * 300 + k] : (_Float16)0.f;
    }
    if (idx < 32000 * 320) {
        int r = idx / 320, k = idx % 320;
        opth[idx] = (k < 300) ? (_Float16)opt[r * 300 + k] : (_Float16)0.f;
    }
}

// ---------------------------------------------------------------------------
// fp16 MFMA GEMM, 64x64 tile, BK=32, 256 threads = 4 waves (2x2 of 32x32).
// C[z] = A[z] * B[z/bdiv]^T + bias, fp32 accumulate, fp16 out.
// TRBS:   B given as [K][N] row-major -> transpose-stage into LDS.
// SPLITA: A = [A|A2] along K (each lda wide, fp16).
// ---------------------------------------------------------------------------
template <bool TRBS, bool SPLITA, bool HASBIAS>
__global__ __launch_bounds__(256, 4) void hgemm_k(
    const _Float16* __restrict__ A, const _Float16* __restrict__ A2,
    const _Float16* __restrict__ B, const float* __restrict__ bias,
    _Float16* __restrict__ C, int M, int N, int K,
    int lda, int ldb, int ldc, long sA, long sB, int bdiv, long sC)
{
    const int jn = blockIdx.x * 64;
    const int im = blockIdx.y * 64;
    const int z  = blockIdx.z;
    const _Float16* Bb = B + (size_t)(z / bdiv) * sB;
    _Float16* Cb = C + (size_t)z * sC;

    __shared__ __align__(16) _Float16 As[64 * 32];
    __shared__ __align__(16) _Float16 Bs[64 * 32];

    const int tid  = threadIdx.x;
    const int arow = tid >> 2;          // 0..63
    const int akof = (tid & 3) * 8;     // 0,8,16,24
    const int lane = tid & 63;
    const int wv   = tid >> 6;          // 0..3
    const int wm   = (wv & 1) * 32;
    const int wn   = (wv >> 1) * 32;
    const int fm   = lane & 15;
    const int quad = lane >> 4;

    f32x4 acc[2][2];
#pragma unroll
    for (int a = 0; a < 2; a++)
#pragma unroll
        for (int b = 0; b < 2; b++) acc[a][b] = (f32x4)0.f;

    for (int k0 = 0; k0 < K; k0 += 32) {
        {
            half8 av = (half8)(_Float16)0.f;
            const int row = im + arow;
            if (row < M) {
                const int kg = k0 + akof;
                if constexpr (SPLITA) {
                    const _Float16* Ah  = A + (size_t)z * sA;
                    const _Float16* A2h = A2 + (size_t)z * sA;
                    const _Float16* ap = (kg < 256) ? (Ah + (size_t)row * lda + kg)
                                                    : (A2h + (size_t)row * lda + (kg - 256));
                    av = *(const half8*)ap;
                } else {
                    av = *(const half8*)(A + (size_t)z * sA + (size_t)row * lda + kg);
                }
            }
            *(half8*)&As[arow * 32 + akof] = av;
        }
        if constexpr (!TRBS) {          // B [N][K] rm (NT)
            half8 bv = *(const half8*)(Bb + (size_t)(jn + arow) * ldb + k0 + akof);
            *(half8*)&Bs[arow * 32 + akof] = bv;
        } else {                        // B [K][N] rm -> LDS [n][k]
            const int kk = tid >> 3, noff = (tid & 7) * 8;
            half8 bv = *(const half8*)(Bb + (size_t)(k0 + kk) * ldb + jn + noff);
#pragma unroll
            for (int e = 0; e < 8; e++) Bs[(noff + e) * 32 + kk] = bv[e];
        }
        __syncthreads();

        const _Float16* Asp = As + (wm + fm) * 32 + quad * 8;
        const _Float16* Bsp = Bs + (wn + fm) * 32 + quad * 8;
        half8 a0 = *(const half8*)Asp;
        half8 a1 = *(const half8*)(Asp + 16 * 32);
        half8 b0 = *(const half8*)Bsp;
        half8 b1 = *(const half8*)(Bsp + 16 * 32);
        acc[0][0] = __builtin_amdgcn_mfma_f32_16x16x32_f16(a0, b0, acc[0][0], 0, 0, 0);
        acc[0][1] = __builtin_amdgcn_mfma_f32_16x16x32_f16(a0, b1, acc[0][1], 0, 0, 0);
        acc[1][0] = __builtin_amdgcn_mfma_f32_16x16x32_f16(a1, b0, acc[1][0], 0, 0, 0);
        acc[1][1] = __builtin_amdgcn_mfma_f32_16x16x32_f16(a1, b1, acc[1][1], 0, 0, 0);
        __syncthreads();
    }

#pragma unroll
    for (int tm = 0; tm < 2; tm++) {
#pragma unroll
        for (int tn = 0; tn < 2; tn++) {
            const int col  = jn + wn + tn * 16 + fm;
            const int row0 = im + wm + tm * 16 + quad * 4;
            const float bv = HASBIAS ? bias[col] : 0.f;
#pragma unroll
            for (int r = 0; r < 4; r++) {
                const int row = row0 + r;
                if (row < M)
                    Cb[(size_t)row * ldc + col] = (_Float16)(acc[tm][tn][r] + bv);
            }
        }
    }
}

// ---------------------------------------------------------------------------
// GRU recurrence v6 (same as R8; logic re-audited clean — R8's failure was a
// workspace-allocation overlap of wr16/wa16, not this kernel).
// One block per (seq,dir); 512 threads = 8 waves. Lane (w,l): owner
// i = w*16 + (l&15), k-quarter kq = l>>4. Each lane computes ALL 3 gate rows
// over its k-quarter (48 fdot2, 48-VGPR fp16x2 weights), __shfl_xor(16/32)
// butterfly sums the 4 k-quarters in-register, gates computed redundantly in
// all replica lanes, h double-buffered in LDS -> ONE barrier per step.
// gx tile-staged in LDS, outs bulk-flushed.
// ---------------------------------------------------------------------------
__global__ __launch_bounds__(512, 2) void gru_rec_k(
    const _Float16* __restrict__ gx,
    const _Float16* __restrict__ whh16,   // [2][384][128] fp16, dir-major
    const float* __restrict__ bhh_f, const float* __restrict__ bhh_b,
    _Float16* __restrict__ outs_h, float* __restrict__ hfin, int L)
{
    const int dir = blockIdx.x & 1;
    const int s   = blockIdx.x >> 1;
    const int t   = threadIdx.x;
    const int w   = t >> 6;
    const int l   = t & 63;
    const int i   = w * 16 + (l & 15);
    const int kq  = l >> 4;
    const _Float16* Wd = whh16 + (size_t)dir * 49152;
    const float* bh = dir ? bhh_b : bhh_f;

    h2_t w2[3][16];
#pragma unroll
    for (int j = 0; j < 3; j++) {
        const _Float16* Wr = Wd + (size_t)(i + 128 * j) * 128 + 32 * kq;
#pragma unroll
        for (int q = 0; q < 16; q++)
            w2[j][q] = *(const h2_t*)(Wr + 2 * q);
    }
    const float b0 = bh[i], b1 = bh[i + 128], b2 = bh[i + 256];

    __shared__ __align__(16) _Float16 h1[2][128];
    __shared__ __align__(16) _Float16 gxs[32][384];
    __shared__ __align__(16) _Float16 outb[32][128];
    if (t < 128) h1[0][t] = (_Float16)0.f;
    float hprev = 0.f;

    for (int t0 = 0; t0 < L; t0 += 32) {
        const int Tc = (L - t0 < 32) ? (L - t0) : 32;
        // stage gx tile (Tc*48 half8 chunks over 512 threads)
#pragma unroll
        for (int r = 0; r < 3; r++) {
            const int q = t + 512 * r;
            if (q < Tc * 48) {
                const int j = q / 48, off = (q % 48) * 8;
                const int tt = dir ? (L - 1 - (t0 + j)) : (t0 + j);
                *(half8*)&gxs[j][off] =
                    *(const half8*)(gx + ((size_t)s * L + tt) * 768 + dir * 384 + off);
            }
        }
        __syncthreads();   // drains staging; orders h1 init / prev flush

        for (int j = 0; j < Tc; j++) {
            const int cb = (t0 + j) & 1;
            const h2_t* hp = (const h2_t*)&h1[cb][32 * kq];
            float a0 = 0.f, a1 = 0.f, a2 = 0.f;
#pragma unroll
            for (int q = 0; q < 16; q++) {
                h2_t hq = hp[q];
                a0 = __builtin_amdgcn_fdot2(w2[0][q], hq, a0, false);
                a1 = __builtin_amdgcn_fdot2(w2[1][q], hq, a1, false);
                a2 = __builtin_amdgcn_fdot2(w2[2][q], hq, a2, false);
            }
            a0 += __shfl_xor(a0, 16); a0 += __shfl_xor(a0, 32);
            a1 += __shfl_xor(a1, 16); a1 += __shfl_xor(a1, 32);
            a2 += __shfl_xor(a2, 16); a2 += __shfl_xor(a2, 32);
            const float xc0 = (float)gxs[j][i];
            const float xc1 = (float)gxs[j][i + 128];
            const float xc2 = (float)gxs[j][i + 256];
            const float r  = fsig(xc0 + a0 + b0);
            const float zz = fsig(xc1 + a1 + b1);
            const float n  = ftanh(xc2 + r * (a2 + b2));
            const float hnew = (1.0f - zz) * n + zz * hprev;
            hprev = hnew;
            if (kq == 0) {
                h1[cb ^ 1][i] = (_Float16)hnew;
                outb[j][i]    = (_Float16)hnew;
            }
            __syncthreads();
        }

        // bulk flush outs tile
        if (outs_h && t < Tc * 16) {
            const int j = t / 16, off = (t % 16) * 8;
            const int tt = dir ? (L - 1 - (t0 + j)) : (t0 + j);
            *(half8*)(outs_h + ((size_t)s * L + tt) * 256 + dir * 128 + off) =
                *(const half8*)&outb[j][off];
        }
    }
    if (hfin && kq == 0) hfin[(size_t)s * 256 + dir * 128 + i] = hprev;
}

// ---------------------------------------------------------------------------
// Row inverse norms over fp16 rows of 256.
// ---------------------------------------------------------------------------
__global__ __launch_bounds__(256) void rowinv_k(const _Float16* __restrict__ x,
                                                float* __restrict__ rinv)
{
    const int row = blockIdx.x;
    float v = (float)x[(size_t)row * 256 + threadIdx.x];
    float ss = v * v;
#pragma unroll
    for (int o = 32; o > 0; o >>= 1) ss += __shfl_down(ss, o);
    __shared__ float ps[4];
    if ((threadIdx.x & 63) == 0) ps[threadIdx.x >> 6] = ss;
    __syncthreads();
    if (threadIdx.x == 0)
        rinv[row] = 1.0f / fmaxf(sqrtf(ps[0] + ps[1] + ps[2] + ps[3]), EPS);
}

// ---------------------------------------------------------------------------
// Fused cosine-scale + softmax (fp16 in/out, 512 positions).
// ---------------------------------------------------------------------------
__global__ __launch_bounds__(256) void att_softmax_k(
    _Float16* __restrict__ att, const float* __restrict__ rinv_opt_l,
    const float* __restrict__ rinv_ctx, int sbase)
{
    const int row = blockIdx.x;
    const int b = (sbase + row / 50) / 10;
    _Float16* p = att + (size_t)row * 512;
    const float* rc = rinv_ctx + b * 512;
    const float sA = rinv_opt_l[row];
    const int t = threadIdx.x;

    float v0 = (float)p[t]       * (sA * rc[t]);
    float v1 = (float)p[t + 256] * (sA * rc[t + 256]);

    __shared__ float red[4];
    float m = fmaxf(v0, v1);
#pragma unroll
    for (int o = 32; o > 0; o >>= 1) m = fmaxf(m, __shfl_down(m, o));
    if ((t & 63) == 0) red[t >> 6] = m;
    __syncthreads();
    m = fmaxf(fmaxf(red[0], red[1]), fmaxf(red[2], red[3]));
    float e0 = __expf(v0 - m), e1 = __expf(v1 - m);
    float ssum = e0 + e1;
#pragma unroll
    for (int o = 32; o > 0; o >>= 1) ssum += __shfl_down(ssum, o);
    __syncthreads();
    if ((t & 63) == 0) red[t >> 6] = ssum;
    __syncthreads();
    float inv = 1.0f / (red[0] + red[1] + red[2] + red[3]);
    p[t]       = (_Float16)(e0 * inv);
    p[t + 256] = (_Float16)(e1 * inv);
}

// ---------------------------------------------------------------------------
// logits[s] = cosine(ctx_h[s/10], ao_h[s])
// ---------------------------------------------------------------------------
__global__ __launch_bounds__(256) void logits_k(const float* __restrict__ ch,
                                                const float* __restrict__ ah,
                                                float* __restrict__ logits)
{
    const int s = blockIdx.x;
    const int b = s / 10;
    const int t = threadIdx.x;
    float a = ch[b * 256 + t];
    float c = ah[(size_t)s * 256 + t];
    float num = a * c, na = a * a, nc = c * c;
#pragma unroll
    for (int o = 32; o > 0; o >>= 1) {
        num += __shfl_down(num, o);
        na  += __shfl_down(na,  o);
        nc  += __shfl_down(nc,  o);
    }
    __shared__ float pn[4], pa[4], pc[4];
    if ((t & 63) == 0) { pn[t >> 6] = num; pa[t >> 6] = na; pc[t >> 6] = nc; }
    __syncthreads();
    if (t == 0) {
        float sn = pn[0] + pn[1] + pn[2] + pn[3];
        float sa = pa[0] + pa[1] + pa[2] + pa[3];
        float sc = pc[0] + pc[1] + pc[2] + pc[3];
        logits[s] = sn / (fmaxf(sqrtf(sa), EPS) * fmaxf(sqrtf(sc), EPS));
    }
}

// ---------------------------------------------------------------------------
__global__ __launch_bounds__(64) void soft10_k(const float* __restrict__ logits,
                                               float* __restrict__ out)
{
    const int b = blockIdx.x;
    const int t = threadIdx.x;
    __shared__ float v[10];
    if (t < 10) v[t] = logits[b * 10 + t];
    __syncthreads();
    if (t < 10) {
        float m = v[0];
#pragma unroll
        for (int i = 1; i < 10; i++) m = fmaxf(m, v[i]);
        float ssum = 0.f;
#pragma unroll
        for (int i = 0; i < 10; i++) ssum += __expf(v[i] - m);
        out[b * 10 + t] = __expf(v[t] - m) / ssum;
    }
}

// ---------------------------------------------------------------------------
extern "C" void kernel_launch(void* const* d_in, const int* in_sizes, int n_in,
                              void* d_out, int out_size, void* d_ws, size_t ws_size,
                              hipStream_t stream)
{
    const float* context = (const float*)d_in[0];
    const float* options = (const float*)d_in[2];
    const float* rw_ih_f = (const float*)d_in[4];
    const float* rw_hh_f = (const float*)d_in[5];
    const float* rb_ih_f = (const float*)d_in[6];
    const float* rb_hh_f = (const float*)d_in[7];
    const float* rw_ih_b = (const float*)d_in[8];
    const float* rw_hh_b = (const float*)d_in[9];
    const float* rb_ih_b = (const float*)d_in[10];
    const float* rb_hh_b = (const float*)d_in[11];
    const float* aw_ih_f = (const float*)d_in[12];
    const float* aw_hh_f = (const float*)d_in[13];
    const float* ab_ih_f = (const float*)d_in[14];
    const float* ab_hh_f = (const float*)d_in[15];
    const float* aw_ih_b = (const float*)d_in[16];
    const float* aw_hh_b = (const float*)d_in[17];
    const float* ab_ih_b = (const float*)d_in[18];
    const float* ab_hh_b = (const float*)d_in[19];

    // --- chunk config. persist(fl) = 15,222,144 (~60.9 MB).
    //     R8 BUG FIX: wr16/wa16 are 98,304 halfs = 49,152 floats EACH
    //     (was 24,576 -> regions overlapped, weights corrupted).
    //     pool = max(bc*196608, sc*19200) fl; extras = sc*25600 fl.
    const size_t persist = 15222144;
    static const int cands[6][2] = {{1,4},{1,8},{2,8},{2,16},{4,16},{8,16}};
    int CC = 8, OC = 16;
    for (int idx = 0; idx < 6; idx++) {
        size_t bc_ = 64 / cands[idx][0], sc_ = 640 / cands[idx][1];
        size_t p = bc_ * 196608;
        if (sc_ * 19200 > p) p = sc_ * 19200;
        if ((persist + p + sc_ * 25600) * 4 <= ws_size) {
            CC = cands[idx][0]; OC = cands[idx][1]; break;
        }
    }
    const int bc = 64 / CC;
    const int sc = 640 / OC;
    size_t poolsz = (size_t)bc * 196608;
    if ((size_t)sc * 19200 > poolsz) poolsz = (size_t)sc * 19200;

    float* ws = (float*)d_ws;
    size_t off = 0;
    _Float16* wrh   = (_Float16*)(ws + off); off += 122880;   // [768][320] h
    float*    br    = ws + off;              off += 768;
    _Float16* wah   = (_Float16*)(ws + off); off += 196608;   // [768][512] h
    float*    ba    = ws + off;              off += 768;
    _Float16* wr16  = (_Float16*)(ws + off); off += 49152;    // [2][384][128] h (98304 halfs)
    _Float16* wa16  = (_Float16*)(ws + off); off += 49152;    // [2][384][128] h (98304 halfs)
    _Float16* couts = (_Float16*)(ws + off); off += 4194304;  // [64*512][256] h
    float*    ctxhf = ws + off;              off += 16384;    // ctx h_fin
    float*    aohf  = ws + off;              off += 163840;   // ao h_fin
    float*    logits= ws + off;              off += 640;
    float*    rinvc = ws + off;              off += 32768;
    float*    rinvo = ws + off;              off += 32000;
    _Float16* ctxh  = (_Float16*)(ws + off); off += 5242880;  // [32768][320] h
    _Float16* opth  = (_Float16*)(ws + off); off += 5120000;  // [32000][320] h
    _Float16* POOL  = (_Float16*)(ws + off); off += poolsz;   // gx (ctx/opt/attn)
    _Float16* ATT   = (_Float16*)(ws + off); off += (size_t)sc * 12800;
    _Float16* P2H   = (_Float16*)(ws + off); off += (size_t)sc * 6400;
    _Float16* P3H   = (_Float16*)(ws + off); off += (size_t)sc * 6400;

    // 1. weights -> fp16; inputs -> fp16 (padded K=320)
    prep_w_k<<<1536, 256, 0, stream>>>(rw_ih_f, rw_ih_b, aw_ih_f, aw_ih_b,
                                       rb_ih_f, rb_ih_b, ab_ih_f, ab_ih_b,
                                       rw_hh_f, rw_hh_b, aw_hh_f, aw_hh_b,
                                       wrh, wah, wr16, wa16, br, ba);
    conv_k<<<40960, 256, 0, stream>>>(context, options, ctxh, opth);

    // 2. context: gx GEMM (MFMA, fp16 A) + GRU per chunk
    for (int c = 0; c < CC; c++) {
        const int Mc = bc * 512;
        hgemm_k<false, false, true><<<dim3(12, Mc / 64, 1), 256, 0, stream>>>(
            ctxh + (size_t)c * Mc * 320, nullptr, wrh, br, POOL,
            Mc, 768, 320, 320, 320, 768, 0, 0, 1, 0);
        gru_rec_k<<<2 * bc, 512, 0, stream>>>(
            POOL, wr16, rb_hh_f, rb_hh_b,
            couts + (size_t)c * Mc * 256, ctxhf + (size_t)c * bc * 256, 512);
    }

    // 3. ctx row inverse norms
    rowinv_k<<<32768, 256, 0, stream>>>(couts, rinvc);

    // 4. options: per chunk pipeline
    for (int o = 0; o < OC; o++) {
        const int base = o * sc;
        const int Mo = sc * 50;
        const _Float16* ctxB = couts + (size_t)(base / 10) * 131072;

        // 4a. opt gx (MFMA) -> POOL
        hgemm_k<false, false, true><<<dim3(12, (Mo + 63) / 64, 1), 256, 0, stream>>>(
            opth + (size_t)base * 50 * 320, nullptr, wrh, br, POOL,
            Mo, 768, 320, 320, 320, 768, 0, 0, 1, 0);
        // 4b. opt GRU -> P2H
        gru_rec_k<<<2 * sc, 512, 0, stream>>>(
            POOL, wr16, rb_hh_f, rb_hh_b, P2H, nullptr, 50);
        // 4c. opt row inverse norms
        rowinv_k<<<Mo, 256, 0, stream>>>(P2H, rinvo + (size_t)base * 50);
        // 4d. raw scores (MFMA, NT, batched): ATT = P2H @ ctxB^T
        hgemm_k<false, false, false><<<dim3(8, 1, sc), 256, 0, stream>>>(
            P2H, nullptr, ctxB, nullptr, ATT,
            50, 512, 256, 256, 256, 512, 12800, 131072, 10, 25600);
        // 4e. fused cosine scaling + softmax (fp16 in-place)
        att_softmax_k<<<Mo, 256, 0, stream>>>(ATT, rinvo + (size_t)base * 50,
                                              rinvc, base);
        // 4f. att_opt (MFMA, NN via transpose-stage): P3H = ATT @ ctxB
        hgemm_k<true, false, false><<<dim3(4, 1, sc), 256, 0, stream>>>(
            ATT, nullptr, ctxB, nullptr, P3H,
            50, 256, 512, 512, 256, 256, 25600, 131072, 10, 12800);
        // 4g. attn gx (MFMA, split-A K=512): POOL = [P3H|P2H] @ wah^T + ba
        hgemm_k<false, true, true><<<dim3(12, (Mo + 63) / 64, 1), 256, 0, stream>>>(
            P3H, P2H, wah, ba, POOL,
            Mo, 768, 512, 256, 512, 768, 0, 0, 1, 0);
        // 4h. attn GRU -> ao_h
        gru_rec_k<<<2 * sc, 512, 0, stream>>>(
            POOL, wa16, ab_hh_f, ab_hh_b, nullptr, aohf + (size_t)base * 256, 50);
    }

    // 5. cosine logits + final softmax
    logits_k<<<640, 256, 0, stream>>>(ctxhf, aohf, logits);
    soft10_k<<<64, 64, 0, stream>>>(logits, (float*)d_out);
}

// Round 10
// 1197.976 us; speedup vs baseline: 1.2510x; 1.1303x over previous
//
#include <hip/hip_runtime.h>
#include <math.h>

#define EPS 1e-8f

typedef _Float16 h2_t __attribute__((ext_vector_type(2)));
typedef _Float16 half8 __attribute__((ext_vector_type(8)));
typedef float f32x4 __attribute__((ext_vector_type(4)));

__device__ __forceinline__ float fsig(float x)  { return 1.0f / (1.0f + __expf(-x)); }
__device__ __forceinline__ float ftanh(float x) { return 1.0f - 2.0f / (1.0f + __expf(2.0f * x)); }

// ---------------------------------------------------------------------------
// Weight prep: W_ih stacks -> fp16 [768,320pad]/[768,512]; W_hh -> fp16
// [2][384][128]; biases fp32.
// ---------------------------------------------------------------------------
__global__ __launch_bounds__(256) void prep_w_k(
    const float* __restrict__ rwf, const float* __restrict__ rwb,
    const float* __restrict__ awf, const float* __restrict__ awb,
    const float* __restrict__ rbf, const float* __restrict__ rbb,
    const float* __restrict__ abf, const float* __restrict__ abb,
    const float* __restrict__ rhf, const float* __restrict__ rhb,
    const float* __restrict__ ahf, const float* __restrict__ ahb,
    _Float16* __restrict__ wrh, _Float16* __restrict__ wah,
    _Float16* __restrict__ wr16, _Float16* __restrict__ wa16,
    float* __restrict__ br, float* __restrict__ ba)
{
    int idx = blockIdx.x * 256 + threadIdx.x;
    if (idx < 768 * 320) {
        int g = idx / 320, k = idx % 320;
        float v = 0.f;
        if (k < 300) v = (g < 384) ? rwf[g * 300 + k] : rwb[(g - 384) * 300 + k];
        wrh[idx] = (_Float16)v;
    }
    if (idx < 768 * 512) {
        int g = idx / 512, k = idx % 512;
        wah[idx] = (_Float16)((g < 384) ? awf[g * 512 + k] : awb[(g - 384) * 512 + k]);
    }
    if (idx < 2 * 384 * 128) {
        int d = idx / 49152, r = idx % 49152;
        wr16[idx] = (_Float16)(d ? rhb[r] : rhf[r]);
        wa16[idx] = (_Float16)(d ? ahb[r] : ahf[r]);
    }
    if (idx < 768) {
        br[idx] = (idx < 384) ? rbf[idx] : rbb[idx - 384];
        ba[idx] = (idx < 384) ? abf[idx] : abb[idx - 384];
    }
}

// ---------------------------------------------------------------------------
// Input conversion fp32 -> fp16 (K padded 300->320 with zeros).
// ---------------------------------------------------------------------------
__global__ __launch_bounds__(256) void conv_k(
    const float* __restrict__ ctx, const float* __restrict__ opt,
    _Float16* __restrict__ ctxh, _Float16* __restrict__ opth)
{
    int idx = blockIdx.x * 256 + threadIdx.x;
    if (idx < 32768 * 320) {
        int r = idx / 320, k = idx % 320;
        ctxh[idx] = (k < 300) ? (_Float16)ctx[r * 300 + k] : (_Float16)0.f;
    }
    if (idx < 32000 * 320) {
        int r = idx / 320, k = idx % 320;
        opth[idx] = (k < 300) ? (_Float16)opt[r * 300 + k] : (_Float16)0.f;
    }
}

// ---------------------------------------------------------------------------
// fp16 MFMA GEMM, 64x64 tile, BK=64 (R10: was 32 -- halves barrier count),
// 256 threads = 4 waves (2x2 of 32x32). C[z] = A[z] * B[z/bdiv]^T + bias,
// fp32 accumulate, fp16 out.
// TRBS:   B given as [K][N] row-major -> transpose-stage into LDS.
// SPLITA: A = [A|A2] along K (each lda wide, fp16).
// K must be a multiple of 64 (320/256/512 all are).
// ---------------------------------------------------------------------------
template <bool TRBS, bool SPLITA, bool HASBIAS>
__global__ __launch_bounds__(256, 4) void hgemm_k(
    const _Float16* __restrict__ A, const _Float16* __restrict__ A2,
    const _Float16* __restrict__ B, const float* __restrict__ bias,
    _Float16* __restrict__ C, int M, int N, int K,
    int lda, int ldb, int ldc, long sA, long sB, int bdiv, long sC)
{
    const int jn = blockIdx.x * 64;
    const int im = blockIdx.y * 64;
    const int z  = blockIdx.z;
    const _Float16* Bb = B + (size_t)(z / bdiv) * sB;
    _Float16* Cb = C + (size_t)z * sC;

    __shared__ __align__(16) _Float16 As[64 * 64];
    __shared__ __align__(16) _Float16 Bs[64 * 64];

    const int tid  = threadIdx.x;
    const int arow = tid >> 2;          // 0..63
    const int akof = (tid & 3) * 8;     // 0,8,16,24
    const int lane = tid & 63;
    const int wv   = tid >> 6;          // 0..3
    const int wm   = (wv & 1) * 32;
    const int wn   = (wv >> 1) * 32;
    const int fm   = lane & 15;
    const int quad = lane >> 4;

    f32x4 acc[2][2];
#pragma unroll
    for (int a = 0; a < 2; a++)
#pragma unroll
        for (int b = 0; b < 2; b++) acc[a][b] = (f32x4)0.f;

    for (int k0 = 0; k0 < K; k0 += 64) {
        // ---- A tile: 64 rows x 64 k (2 half8 per thread)
        {
            const int row = im + arow;
#pragma unroll
            for (int hh = 0; hh < 2; hh++) {
                half8 av = (half8)(_Float16)0.f;
                const int kg = k0 + akof + 32 * hh;
                if (row < M) {
                    if constexpr (SPLITA) {
                        const _Float16* Ah  = A + (size_t)z * sA;
                        const _Float16* A2h = A2 + (size_t)z * sA;
                        const _Float16* ap = (kg < 256)
                            ? (Ah + (size_t)row * lda + kg)
                            : (A2h + (size_t)row * lda + (kg - 256));
                        av = *(const half8*)ap;
                    } else {
                        av = *(const half8*)(A + (size_t)z * sA + (size_t)row * lda + kg);
                    }
                }
                *(half8*)&As[arow * 64 + akof + 32 * hh] = av;
            }
        }
        // ---- B tile
        if constexpr (!TRBS) {          // B [N][K] rm (NT)
#pragma unroll
            for (int hh = 0; hh < 2; hh++) {
                half8 bv = *(const half8*)(Bb + (size_t)(jn + arow) * ldb
                                           + k0 + akof + 32 * hh);
                *(half8*)&Bs[arow * 64 + akof + 32 * hh] = bv;
            }
        } else {                        // B [K][N] rm -> LDS [n][k]
            const int kk = tid >> 3, noff = (tid & 7) * 8;
            half8 bv0 = *(const half8*)(Bb + (size_t)(k0 + kk) * ldb + jn + noff);
            half8 bv1 = *(const half8*)(Bb + (size_t)(k0 + kk + 32) * ldb + jn + noff);
#pragma unroll
            for (int e = 0; e < 8; e++) {
                Bs[(noff + e) * 64 + kk]      = bv0[e];
                Bs[(noff + e) * 64 + kk + 32] = bv1[e];
            }
        }
        __syncthreads();

        const _Float16* Asp = As + (wm + fm) * 64 + quad * 8;
        const _Float16* Bsp = Bs + (wn + fm) * 64 + quad * 8;
#pragma unroll
        for (int kh = 0; kh < 64; kh += 32) {
            half8 a0 = *(const half8*)(Asp + kh);
            half8 a1 = *(const half8*)(Asp + 16 * 64 + kh);
            half8 b0 = *(const half8*)(Bsp + kh);
            half8 b1 = *(const half8*)(Bsp + 16 * 64 + kh);
            acc[0][0] = __builtin_amdgcn_mfma_f32_16x16x32_f16(a0, b0, acc[0][0], 0, 0, 0);
            acc[0][1] = __builtin_amdgcn_mfma_f32_16x16x32_f16(a0, b1, acc[0][1], 0, 0, 0);
            acc[1][0] = __builtin_amdgcn_mfma_f32_16x16x32_f16(a1, b0, acc[1][0], 0, 0, 0);
            acc[1][1] = __builtin_amdgcn_mfma_f32_16x16x32_f16(a1, b1, acc[1][1], 0, 0, 0);
        }
        __syncthreads();
    }

#pragma unroll
    for (int tm = 0; tm < 2; tm++) {
#pragma unroll
        for (int tn = 0; tn < 2; tn++) {
            const int col  = jn + wn + tn * 16 + fm;
            const int row0 = im + wm + tm * 16 + quad * 4;
            const float bv = HASBIAS ? bias[col] : 0.f;
#pragma unroll
            for (int r = 0; r < 4; r++) {
                const int row = row0 + r;
                if (row < M)
                    Cb[(size_t)row * ldc + col] = (_Float16)(acc[tm][tn][r] + bv);
            }
        }
    }
}

// ---------------------------------------------------------------------------
// GRU recurrence v7 = v6 with Tc=64 (half the staging barriers; L=50 becomes
// single-tile). Step cost is LDS-pipe-bound (~1670 cyc): 32 ds_read_b128 for
// h broadcast + 48 ds_bpermute (shuffles) + gxs/outb per step serialize
// through the CU's one LDS unit; v5 (2-barrier LDS-dump) == v6 (1-barrier
// shuffle) confirms. Cutting it needs more rows/lane => >48 weight VGPRs =>
// the spill wall (hit in v2/v3/v4). Accepted for now.
// ---------------------------------------------------------------------------
__global__ __launch_bounds__(512, 2) void gru_rec_k(
    const _Float16* __restrict__ gx,
    const _Float16* __restrict__ whh16,   // [2][384][128] fp16, dir-major
    const float* __restrict__ bhh_f, const float* __restrict__ bhh_b,
    _Float16* __restrict__ outs_h, float* __restrict__ hfin, int L)
{
    const int dir = blockIdx.x & 1;
    const int s   = blockIdx.x >> 1;
    const int t   = threadIdx.x;
    const int w   = t >> 6;
    const int l   = t & 63;
    const int i   = w * 16 + (l & 15);
    const int kq  = l >> 4;
    const _Float16* Wd = whh16 + (size_t)dir * 49152;
    const float* bh = dir ? bhh_b : bhh_f;

    h2_t w2[3][16];
#pragma unroll
    for (int j = 0; j < 3; j++) {
        const _Float16* Wr = Wd + (size_t)(i + 128 * j) * 128 + 32 * kq;
#pragma unroll
        for (int q = 0; q < 16; q++)
            w2[j][q] = *(const h2_t*)(Wr + 2 * q);
    }
    const float b0 = bh[i], b1 = bh[i + 128], b2 = bh[i + 256];

    __shared__ __align__(16) _Float16 h1[2][128];
    __shared__ __align__(16) _Float16 gxs[64][384];
    __shared__ __align__(16) _Float16 outb[64][128];
    if (t < 128) h1[0][t] = (_Float16)0.f;
    float hprev = 0.f;

    for (int t0 = 0; t0 < L; t0 += 64) {
        const int Tc = (L - t0 < 64) ? (L - t0) : 64;
        // stage gx tile (Tc*48 half8 chunks over 512 threads)
#pragma unroll
        for (int r = 0; r < 6; r++) {
            const int q = t + 512 * r;
            if (q < Tc * 48) {
                const int j = q / 48, off = (q % 48) * 8;
                const int tt = dir ? (L - 1 - (t0 + j)) : (t0 + j);
                *(half8*)&gxs[j][off] =
                    *(const half8*)(gx + ((size_t)s * L + tt) * 768 + dir * 384 + off);
            }
        }
        __syncthreads();   // drains staging; orders h1 init / prev flush

        for (int j = 0; j < Tc; j++) {
            const int cb = (t0 + j) & 1;
            const h2_t* hp = (const h2_t*)&h1[cb][32 * kq];
            float a0 = 0.f, a1 = 0.f, a2 = 0.f;
#pragma unroll
            for (int q = 0; q < 16; q++) {
                h2_t hq = hp[q];
                a0 = __builtin_amdgcn_fdot2(w2[0][q], hq, a0, false);
                a1 = __builtin_amdgcn_fdot2(w2[1][q], hq, a1, false);
                a2 = __builtin_amdgcn_fdot2(w2[2][q], hq, a2, false);
            }
            a0 += __shfl_xor(a0, 16); a0 += __shfl_xor(a0, 32);
            a1 += __shfl_xor(a1, 16); a1 += __shfl_xor(a1, 32);
            a2 += __shfl_xor(a2, 16); a2 += __shfl_xor(a2, 32);
            const float xc0 = (float)gxs[j][i];
            const float xc1 = (float)gxs[j][i + 128];
            const float xc2 = (float)gxs[j][i + 256];
            const float r  = fsig(xc0 + a0 + b0);
            const float zz = fsig(xc1 + a1 + b1);
            const float n  = ftanh(xc2 + r * (a2 + b2));
            const float hnew = (1.0f - zz) * n + zz * hprev;
            hprev = hnew;
            if (kq == 0) {
                h1[cb ^ 1][i] = (_Float16)hnew;
                outb[j][i]    = (_Float16)hnew;
            }
            __syncthreads();
        }

        // bulk flush outs tile (Tc*16 half8 chunks)
        if (outs_h) {
#pragma unroll
            for (int r = 0; r < 2; r++) {
                const int q = t + 512 * r;
                if (q < Tc * 16) {
                    const int j = q / 16, off = (q % 16) * 8;
                    const int tt = dir ? (L - 1 - (t0 + j)) : (t0 + j);
                    *(half8*)(outs_h + ((size_t)s * L + tt) * 256 + dir * 128 + off) =
                        *(const half8*)&outb[j][off];
                }
            }
        }
    }
    if (hfin && kq == 0) hfin[(size_t)s * 256 + dir * 128 + i] = hprev;
}

// ---------------------------------------------------------------------------
// Row inverse norms over fp16 rows of 256.
// ---------------------------------------------------------------------------
__global__ __launch_bounds__(256) void rowinv_k(const _Float16* __restrict__ x,
                                                float* __restrict__ rinv)
{
    const int row = blockIdx.x;
    float v = (float)x[(size_t)row * 256 + threadIdx.x];
    float ss = v * v;
#pragma unroll
    for (int o = 32; o > 0; o >>= 1) ss += __shfl_down(ss, o);
    __shared__ float ps[4];
    if ((threadIdx.x & 63) == 0) ps[threadIdx.x >> 6] = ss;
    __syncthreads();
    if (threadIdx.x == 0)
        rinv[row] = 1.0f / fmaxf(sqrtf(ps[0] + ps[1] + ps[2] + ps[3]), EPS);
}

// ---------------------------------------------------------------------------
// Fused cosine-scale + softmax (fp16 in/out, 512 positions).
// ---------------------------------------------------------------------------
__global__ __launch_bounds__(256) void att_softmax_k(
    _Float16* __restrict__ att, const float* __restrict__ rinv_opt_l,
    const float* __restrict__ rinv_ctx, int sbase)
{
    const int row = blockIdx.x;
    const int b = (sbase + row / 50) / 10;
    _Float16* p = att + (size_t)row * 512;
    const float* rc = rinv_ctx + b * 512;
    const float sA = rinv_opt_l[row];
    const int t = threadIdx.x;

    float v0 = (float)p[t]       * (sA * rc[t]);
    float v1 = (float)p[t + 256] * (sA * rc[t + 256]);

    __shared__ float red[4];
    float m = fmaxf(v0, v1);
#pragma unroll
    for (int o = 32; o > 0; o >>= 1) m = fmaxf(m, __shfl_down(m, o));
    if ((t & 63) == 0) red[t >> 6] = m;
    __syncthreads();
    m = fmaxf(fmaxf(red[0], red[1]), fmaxf(red[2], red[3]));
    float e0 = __expf(v0 - m), e1 = __expf(v1 - m);
    float ssum = e0 + e1;
#pragma unroll
    for (int o = 32; o > 0; o >>= 1) ssum += __shfl_down(ssum, o);
    __syncthreads();
    if ((t & 63) == 0) red[t >> 6] = ssum;
    __syncthreads();
    float inv = 1.0f / (red[0] + red[1] + red[2] + red[3]);
    p[t]       = (_Float16)(e0 * inv);
    p[t + 256] = (_Float16)(e1 * inv);
}

// ---------------------------------------------------------------------------
// logits[s] = cosine(ctx_h[s/10], ao_h[s])
// ---------------------------------------------------------------------------
__global__ __launch_bounds__(256) void logits_k(const float* __restrict__ ch,
                                                const float* __restrict__ ah,
                                                float* __restrict__ logits)
{
    const int s = blockIdx.x;
    const int b = s / 10;
    const int t = threadIdx.x;
    float a = ch[b * 256 + t];
    float c = ah[(size_t)s * 256 + t];
    float num = a * c, na = a * a, nc = c * c;
#pragma unroll
    for (int o = 32; o > 0; o >>= 1) {
        num += __shfl_down(num, o);
        na  += __shfl_down(na,  o);
        nc  += __shfl_down(nc,  o);
    }
    __shared__ float pn[4], pa[4], pc[4];
    if ((t & 63) == 0) { pn[t >> 6] = num; pa[t >> 6] = na; pc[t >> 6] = nc; }
    __syncthreads();
    if (t == 0) {
        float sn = pn[0] + pn[1] + pn[2] + pn[3];
        float sa = pa[0] + pa[1] + pa[2] + pa[3];
        float sc = pc[0] + pc[1] + pc[2] + pc[3];
        logits[s] = sn / (fmaxf(sqrtf(sa), EPS) * fmaxf(sqrtf(sc), EPS));
    }
}

// ---------------------------------------------------------------------------
__global__ __launch_bounds__(64) void soft10_k(const float* __restrict__ logits,
                                               float* __restrict__ out)
{
    const int b = blockIdx.x;
    const int t = threadIdx.x;
    __shared__ float v[10];
    if (t < 10) v[t] = logits[b * 10 + t];
    __syncthreads();
    if (t < 10) {
        float m = v[0];
#pragma unroll
        for (int i = 1; i < 10; i++) m = fmaxf(m, v[i]);
        float ssum = 0.f;
#pragma unroll
        for (int i = 0; i < 10; i++) ssum += __expf(v[i] - m);
        out[b * 10 + t] = __expf(v[t] - m) / ssum;
    }
}

// ---------------------------------------------------------------------------
extern "C" void kernel_launch(void* const* d_in, const int* in_sizes, int n_in,
                              void* d_out, int out_size, void* d_ws, size_t ws_size,
                              hipStream_t stream)
{
    const float* context = (const float*)d_in[0];
    const float* options = (const float*)d_in[2];
    const float* rw_ih_f = (const float*)d_in[4];
    const float* rw_hh_f = (const float*)d_in[5];
    const float* rb_ih_f = (const float*)d_in[6];
    const float* rb_hh_f = (const float*)d_in[7];
    const float* rw_ih_b = (const float*)d_in[8];
    const float* rw_hh_b = (const float*)d_in[9];
    const float* rb_ih_b = (const float*)d_in[10];
    const float* rb_hh_b = (const float*)d_in[11];
    const float* aw_ih_f = (const float*)d_in[12];
    const float* aw_hh_f = (const float*)d_in[13];
    const float* ab_ih_f = (const float*)d_in[14];
    const float* ab_hh_f = (const float*)d_in[15];
    const float* aw_ih_b = (const float*)d_in[16];
    const float* aw_hh_b = (const float*)d_in[17];
    const float* ab_ih_b = (const float*)d_in[18];
    const float* ab_hh_b = (const float*)d_in[19];

    // --- chunk config. persist(fl) = 15,222,144 (~60.9 MB).
    //     R10: ATT lives INSIDE the POOL (disjoint lifetimes: opt-gx
    //     [0 .. sc*19200), ATT [sc*19200 .. sc*32000), attn-gx reuses
    //     [0 .. sc*19200) after opt-gx is dead). pool = max(bc*196608,
    //     sc*32000); extras = 2*sc*6400 (P2H,P3H).
    //     {1,2} total = 31,901,056 fl -- identical to R9's proven fit.
    const size_t persist = 15222144;
    static const int cands[6][2] = {{1,2},{1,4},{2,4},{2,8},{4,16},{8,16}};
    int CC = 8, OC = 16;
    for (int idx = 0; idx < 6; idx++) {
        size_t bc_ = 64 / cands[idx][0], sc_ = 640 / cands[idx][1];
        size_t p = bc_ * 196608;
        if (sc_ * 32000 > p) p = sc_ * 32000;
        if ((persist + p + 2 * sc_ * 6400) * 4 <= ws_size) {
            CC = cands[idx][0]; OC = cands[idx][1]; break;
        }
    }
    const int bc = 64 / CC;
    const int sc = 640 / OC;
    size_t poolsz = (size_t)bc * 196608;
    if ((size_t)sc * 32000 > poolsz) poolsz = (size_t)sc * 32000;

    float* ws = (float*)d_ws;
    size_t off = 0;
    _Float16* wrh   = (_Float16*)(ws + off); off += 122880;   // [768][320] h
    float*    br    = ws + off;              off += 768;
    _Float16* wah   = (_Float16*)(ws + off); off += 196608;   // [768][512] h
    float*    ba    = ws + off;              off += 768;
    _Float16* wr16  = (_Float16*)(ws + off); off += 49152;    // [2][384][128] h
    _Float16* wa16  = (_Float16*)(ws + off); off += 49152;    // [2][384][128] h
    _Float16* couts = (_Float16*)(ws + off); off += 4194304;  // [64*512][256] h
    float*    ctxhf = ws + off;              off += 16384;    // ctx h_fin
    float*    aohf  = ws + off;              off += 163840;   // ao h_fin
    float*    logits= ws + off;              off += 640;
    float*    rinvc = ws + off;              off += 32768;
    float*    rinvo = ws + off;              off += 32000;
    _Float16* ctxh  = (_Float16*)(ws + off); off += 5242880;  // [32768][320] h
    _Float16* opth  = (_Float16*)(ws + off); off += 5120000;  // [32000][320] h
    _Float16* POOL  = (_Float16*)(ws + off); off += poolsz;   // gx pool (+ATT)
    _Float16* P2H   = (_Float16*)(ws + off); off += (size_t)sc * 6400;
    _Float16* P3H   = (_Float16*)(ws + off); off += (size_t)sc * 6400;
    _Float16* ATT   = POOL + (size_t)sc * 38400;  // halfs offset (= sc*19200 fl)

    // 1. weights -> fp16; inputs -> fp16 (padded K=320)
    prep_w_k<<<1536, 256, 0, stream>>>(rw_ih_f, rw_ih_b, aw_ih_f, aw_ih_b,
                                       rb_ih_f, rb_ih_b, ab_ih_f, ab_ih_b,
                                       rw_hh_f, rw_hh_b, aw_hh_f, aw_hh_b,
                                       wrh, wah, wr16, wa16, br, ba);
    conv_k<<<40960, 256, 0, stream>>>(context, options, ctxh, opth);

    // 2. context: gx GEMM (MFMA) + GRU per chunk
    for (int c = 0; c < CC; c++) {
        const int Mc = bc * 512;
        hgemm_k<false, false, true><<<dim3(12, Mc / 64, 1), 256, 0, stream>>>(
            ctxh + (size_t)c * Mc * 320, nullptr, wrh, br, POOL,
            Mc, 768, 320, 320, 320, 768, 0, 0, 1, 0);
        gru_rec_k<<<2 * bc, 512, 0, stream>>>(
            POOL, wr16, rb_hh_f, rb_hh_b,
            couts + (size_t)c * Mc * 256, ctxhf + (size_t)c * bc * 256, 512);
    }

    // 3. ctx row inverse norms
    rowinv_k<<<32768, 256, 0, stream>>>(couts, rinvc);

    // 4. options: per chunk pipeline
    for (int o = 0; o < OC; o++) {
        const int base = o * sc;
        const int Mo = sc * 50;
        const _Float16* ctxB = couts + (size_t)(base / 10) * 131072;

        // 4a. opt gx (MFMA) -> POOL[0 .. sc*38400 halfs)
        hgemm_k<false, false, true><<<dim3(12, (Mo + 63) / 64, 1), 256, 0, stream>>>(
            opth + (size_t)base * 50 * 320, nullptr, wrh, br, POOL,
            Mo, 768, 320, 320, 320, 768, 0, 0, 1, 0);
        // 4b. opt GRU -> P2H   (opt gx dead after this)
        gru_rec_k<<<2 * sc, 512, 0, stream>>>(
            POOL, wr16, rb_hh_f, rb_hh_b, P2H, nullptr, 50);
        // 4c. opt row inverse norms
        rowinv_k<<<Mo, 256, 0, stream>>>(P2H, rinvo + (size_t)base * 50);
        // 4d. raw scores (MFMA, NT, batched): ATT = P2H @ ctxB^T
        hgemm_k<false, false, false><<<dim3(8, 1, sc), 256, 0, stream>>>(
            P2H, nullptr, ctxB, nullptr, ATT,
            50, 512, 256, 256, 256, 512, 12800, 131072, 10, 25600);
        // 4e. fused cosine scaling + softmax (fp16 in-place)
        att_softmax_k<<<Mo, 256, 0, stream>>>(ATT, rinvo + (size_t)base * 50,
                                              rinvc, base);
        // 4f. att_opt (MFMA, NN via transpose-stage): P3H = ATT @ ctxB
        hgemm_k<true, false, false><<<dim3(4, 1, sc), 256, 0, stream>>>(
            ATT, nullptr, ctxB, nullptr, P3H,
            50, 256, 512, 512, 256, 256, 25600, 131072, 10, 12800);
        // 4g. attn gx (MFMA, split-A K=512) -> POOL[0 ..) (opt-gx region, dead)
        hgemm_k<false, true, true><<<dim3(12, (Mo + 63) / 64, 1), 256, 0, stream>>>(
            P3H, P2H, wah, ba, POOL,
            Mo, 768, 512, 256, 512, 768, 0, 0, 1, 0);
        // 4h. attn GRU -> ao_h
        gru_rec_k<<<2 * sc, 512, 0, stream>>>(
            POOL, wa16, ab_hh_f, ab_hh_b, nullptr, aohf + (size_t)base * 256, 50);
    }

    // 5. cosine logits + final softmax
    logits_k<<<640, 256, 0, stream>>>(ctxhf, aohf, logits);
    soft10_k<<<64, 64, 0, stream>>>(logits, (float*)d_out);
}